// Round 1
// 433.830 us; speedup vs baseline: 1.0049x; 1.0049x over previous
//
#include <hip/hip_runtime.h>
#include <stdint.h>

typedef _Float16 h2 __attribute__((ext_vector_type(2)));

#define N_CLUSTERS 100
#define M 10
#define HS 5
#define HM 50
#define GROUP 64
#define TILES 4
#define NWAVE 16
#define XPITCH_B 2004      // f16 row pitch: 501 words, odd -> 2-way bank = free

// LDS layout (bytes):
//  resident:
//   xg   @ 0      : 64*2004 = 128256   (meta scratch overlaid after phase 1)
//   lwe  @ 128256 : W_enc f16x2 [c][k*5+p], pitch 104 B  = 10400  (staged ONCE)
//   lwd  @ 138656 : W_dec f16x2 [c][m*3+q], pitch 120 B  = 12000  (staged ONCE)
//   errL @ 150656 : err f16 [row][c], pitch 200 B        = 12800  -> 163456
//  overlay on xg (dead between phase-1 barrier and end-of-tile xg rewrite):
//   we1p @ 0      : We1^T f16x2 [j][cp], pitch 104 B     = 5200
//   wd1p @ 5200   : Wd1^T f16x2 [c][jp], pitch 104 B     = 10400
//   hmp  @ 15600  : hm f16x2 [jp][row] u32               = 6400
//   part @ 22000  : f32 [16][64]                         = 4096
#define O_WE1T 0
#define O_WD1T 5200
#define O_HMT  15600
#define O_PART 22000
#define O_LWE  128256
#define O_LWD  138656
#define O_ERR  150656
#define LDS_TOTAL 163456

__device__ __forceinline__ float fdot2(uint32_t a, uint32_t b, float c) {
    return __builtin_amdgcn_fdot2(__builtin_bit_cast(h2, a),
                                  __builtin_bit_cast(h2, b), c, false);
}
__device__ __forceinline__ uint32_t pk2(float a, float b) {
    return __builtin_bit_cast(uint32_t, __builtin_amdgcn_cvt_pkrtz(a, b));
}
__device__ __forceinline__ float h2f(unsigned short u) {
    return (float)__builtin_bit_cast(_Float16, u);
}

__global__ void __launch_bounds__(1024) kitnet_kernel(
    const float* __restrict__ x,
    const int*   __restrict__ fi,
    const float* __restrict__ W_enc, const float* __restrict__ b_enc,
    const float* __restrict__ W_dec, const float* __restrict__ b_dec,
    const float* __restrict__ We1,   const float* __restrict__ be1,
    const float* __restrict__ Wd1,   const float* __restrict__ bd1,
    float* __restrict__ out)
{
    extern __shared__ char smem[];
    const int tid  = threadIdx.x;
    const int lane = tid & 63;
    const int w    = __builtin_amdgcn_readfirstlane(tid >> 6);

    uint32_t* lweU = (uint32_t*)(smem + O_LWE);   // pitch 26 u32
    uint32_t* lwdU = (uint32_t*)(smem + O_LWD);   // pitch 30 u32
    unsigned short* errL = (unsigned short*)(smem + O_ERR); // pitch 100 u16

    // ---- tile load helpers: issue 16 loads deep, convert+write later ----
    auto load_x = [&](float4 (&vb)[16], int row0) {
        const float4* xr = (const float4*)(x + (size_t)row0 * 1000);
        #pragma unroll
        for (int k = 0; k < 16; ++k) {
            int i = tid + (k << 10);
            if (i < 16000) vb[k] = xr[i];
        }
    };
    auto write_x = [&](float4 (&vb)[16]) {
        #pragma unroll
        for (int k = 0; k < 16; ++k) {
            int i = tid + (k << 10);
            if (i < 16000) {
                int row = i / 250;
                int c4  = i - row * 250;
                uint32_t* p = (uint32_t*)(smem + row * XPITCH_B + c4 * 8);
                p[0] = pk2(vb[k].x, vb[k].y);
                p[1] = pk2(vb[k].z, vb[k].w);
            }
        }
    };

    const int rowbase = blockIdx.x * (GROUP * TILES);

    // ---- prologue: issue tile-0 loads, stage AE weights ONCE, write tile 0 ----
    float4 vbuf[16];
    load_x(vbuf, rowbase);
    for (int i = tid; i < 2500; i += 1024) {       // W_enc -> [c][k*5+p] m-pairs
        int c = i / 25, r = i - c * 25;
        int k = r / 5, pp = r - k * 5;
        lweU[c * 26 + r] = pk2(W_enc[c * 50 + (2 * pp) * 5 + k],
                               W_enc[c * 50 + (2 * pp + 1) * 5 + k]);
    }
    for (int i = tid; i < 3000; i += 1024) {       // W_dec -> [c][m*3+q] k-pairs
        int c = i / 30, r = i - c * 30;
        int m = r / 3, q = r - m * 3;
        float lo = W_dec[c * 50 + (2 * q) * 10 + m];
        float hi = (q == 2) ? 0.f : W_dec[c * 50 + (2 * q + 1) * 10 + m];
        lwdU[c * 30 + r] = pk2(lo, hi);
    }
    write_x(vbuf);
    __syncthreads();

    // ---- per-cluster AE (phase 1 body), lane = row ----
    const unsigned short* myrow = (const unsigned short*)(smem + lane * XPITCH_B);
    auto do_cluster = [&](int c) {
        int cols[M];
        #pragma unroll
        for (int m = 0; m < M; ++m) cols[m] = fi[c * 10 + m];   // uniform s_load
        uint32_t xpk[5];
        #pragma unroll
        for (int p = 0; p < 5; ++p)
            xpk[p] = (uint32_t)myrow[cols[2 * p]] |
                     ((uint32_t)myrow[cols[2 * p + 1]] << 16);
        // encoder: 25 dot2
        const uint2* eW = (const uint2*)(lweU + c * 26);
        uint32_t wreg[25];
        #pragma unroll
        for (int q = 0; q < 12; ++q) { uint2 t = eW[q]; wreg[2*q] = t.x; wreg[2*q+1] = t.y; }
        wreg[24] = (lweU + c * 26)[24];
        float h[HS];
        #pragma unroll
        for (int k = 0; k < HS; ++k) h[k] = b_enc[c * 5 + k];
        #pragma unroll
        for (int k = 0; k < HS; ++k) {
            #pragma unroll
            for (int p = 0; p < 5; ++p)
                h[k] = fdot2(xpk[p], wreg[k * 5 + p], h[k]);
        }
        uint32_t hp[3];
        hp[0] = pk2(fmaxf(h[0], 0.f), fmaxf(h[1], 0.f));
        hp[1] = pk2(fmaxf(h[2], 0.f), fmaxf(h[3], 0.f));
        hp[2] = pk2(fmaxf(h[4], 0.f), 0.f);
        // decoder: 30 dot2
        const uint2* dW = (const uint2*)(lwdU + c * 30);
        uint32_t dreg[30];
        #pragma unroll
        for (int q = 0; q < 15; ++q) { uint2 t = dW[q]; dreg[2*q] = t.x; dreg[2*q+1] = t.y; }
        float acc = 0.f;
        #pragma unroll
        for (int m = 0; m < M; ++m) {
            float r = b_dec[c * 10 + m];
            r = fdot2(hp[0], dreg[m * 3 + 0], r);
            r = fdot2(hp[1], dreg[m * 3 + 1], r);
            r = fdot2(hp[2], dreg[m * 3 + 2], r);
            h2 xv = __builtin_bit_cast(h2, xpk[m >> 1]);
            float xf = (float)((m & 1) ? xv.y : xv.x);
            float d = xf - r;
            acc = __builtin_fmaf(d, d, acc);
        }
        _Float16 ev = (_Float16)__builtin_sqrtf(acc * 0.1f);
        errL[lane * 100 + c] = __builtin_bit_cast(unsigned short, ev);
    };

    // ---- meta helpers (loop-invariant pointers) ----
    uint32_t* we1U = (uint32_t*)(smem + O_WE1T);  // [j][cp], pitch 26 u32
    uint32_t* wd1U = (uint32_t*)(smem + O_WD1T);  // [c][jp], pitch 26 u32
    uint32_t* hmp  = (uint32_t*)(smem + O_HMT);   // [p][lane]
    float*    part = (float*)(smem + O_PART);
    const uint2* e2 = (const uint2*)(errL + lane * 100);
    auto do_pair = [&](int p) {
        const int j0 = 2 * p;
        float a0 = be1[j0], a1 = be1[j0 + 1];     // uniform s_load
        const uint2* w0 = (const uint2*)(we1U + j0 * 26);
        const uint2* w1 = (const uint2*)(we1U + (j0 + 1) * 26);
        #pragma unroll
        for (int ch = 0; ch < 12; ++ch) {
            uint2 e = e2[ch]; uint2 wa = w0[ch]; uint2 wb = w1[ch];
            a0 = fdot2(e.x, wa.x, a0); a0 = fdot2(e.y, wa.y, a0);
            a1 = fdot2(e.x, wb.x, a1); a1 = fdot2(e.y, wb.y, a1);
        }
        uint32_t et = ((const uint32_t*)e2)[24];
        a0 = fdot2(et, (we1U + j0 * 26)[24], a0);
        a1 = fdot2(et, (we1U + (j0 + 1) * 26)[24], a1);
        hmp[p * 64 + lane] = pk2(fmaxf(a0, 0.f), fmaxf(a1, 0.f));
    };

    // ================= tile loop: 4 tiles per block, 1 block per CU =========
    #pragma unroll 1
    for (int t = 0; t < TILES; ++t) {
        const int b0t = rowbase + t * GROUP;

        // ---- phase 1: cluster AEs on tile t (last use of xg(t)) ----
        #pragma unroll 2
        for (int u = 0; u < 6; ++u) do_cluster(w + 16 * u);
        if (w < 4) do_cluster(w + 96);
        __syncthreads();

        // ---- issue tile t+1 global loads NOW (xg dead; latency hides under
        //      phases 2-4; 64 VGPRs in flight while reg pressure is low) ----
        if (t + 1 < TILES) load_x(vbuf, b0t + GROUP);

        // ---- phase 2: stage meta weights transposed+paired into dead xg ----
        for (int i = tid; i < 1250; i += 1024) {
            int j = i / 25, cp = i - j * 25;
            we1U[j * 26 + cp] = pk2(We1[(2 * cp) * 50 + j], We1[(2 * cp + 1) * 50 + j]);
        }
        for (int i = tid; i < 2500; i += 1024) {
            int c = i / 25, jp = i - c * 25;
            wd1U[c * 26 + jp] = pk2(Wd1[(2 * jp) * 100 + c], Wd1[(2 * jp + 1) * 100 + c]);
        }
        __syncthreads();

        // ---- phase 3: meta encoder; j-pair p = w (+16 if w<9) ----
        do_pair(w);
        if (w < 9) do_pair(w + 16);
        __syncthreads();

        // ---- phase 4: meta decoder + final RMS ----
        uint32_t hmreg[25];
        #pragma unroll
        for (int p = 0; p < 25; ++p) hmreg[p] = hmp[p * 64 + lane];  // conflict-free
        float facc = 0.f;
        auto do_dec = [&](int c) {
            float er = h2f(errL[lane * 100 + c]);
            float r = bd1[c];                      // uniform s_load
            const uint2* wr = (const uint2*)(wd1U + c * 26);
            #pragma unroll
            for (int q = 0; q < 12; ++q) {
                uint2 tt = wr[q];
                r = fdot2(hmreg[2 * q], tt.x, r);
                r = fdot2(hmreg[2 * q + 1], tt.y, r);
            }
            r = fdot2(hmreg[24], (wd1U + c * 26)[24], r);
            float d = er - r;
            facc = __builtin_fmaf(d, d, facc);
        };
        #pragma unroll 2
        for (int u = 0; u < 6; ++u) do_dec(w + 16 * u);
        if (w < 4) do_dec(w + 96);
        part[w * 64 + lane] = facc;
        __syncthreads();

        // ---- reduce + store (reads part, which overlays xg @22000) ----
        if (tid < 64) {
            float s = 0.f;
            #pragma unroll
            for (int i = 0; i < NWAVE; ++i) s += part[i * 64 + tid];
            float fe = __builtin_sqrtf(s * 0.01f);
            out[b0t + tid] = 1.f / (1.f + __expf(-fe));
        }
        __syncthreads();   // part reads done before xg rewrite clobbers overlay

        // ---- convert + write tile t+1 into xg (loads long since arrived) ----
        if (t + 1 < TILES) write_x(vbuf);
        __syncthreads();   // xg(t+1) ready for next phase 1
    }
}

extern "C" void kernel_launch(void* const* d_in, const int* in_sizes, int n_in,
                              void* d_out, int out_size, void* d_ws, size_t ws_size,
                              hipStream_t stream) {
    const float* x     = (const float*)d_in[0];
    const int*   fi    = (const int*)  d_in[1];
    const float* W_enc = (const float*)d_in[2];
    const float* b_enc = (const float*)d_in[3];
    const float* W_dec = (const float*)d_in[4];
    const float* b_dec = (const float*)d_in[5];
    const float* We1   = (const float*)d_in[6];
    const float* be1   = (const float*)d_in[7];
    const float* Wd1   = (const float*)d_in[8];
    const float* bd1   = (const float*)d_in[9];
    float* out = (float*)d_out;

    (void)hipFuncSetAttribute((const void*)kitnet_kernel,
                              hipFuncAttributeMaxDynamicSharedMemorySize, LDS_TOTAL);
    kitnet_kernel<<<65536 / (GROUP * TILES), 1024, LDS_TOTAL, stream>>>(
        x, fi, W_enc, b_enc, W_dec, b_dec, We1, be1, Wd1, bd1, out);
}

// Round 2
// 403.665 us; speedup vs baseline: 1.0799x; 1.0747x over previous
//
#include <hip/hip_runtime.h>
#include <stdint.h>

typedef _Float16 h2 __attribute__((ext_vector_type(2)));

#define N_CLUSTERS 100
#define M 10
#define HS 5
#define HM 50
#define GROUP 64
#define TILES 4
#define NWAVE 16
#define XPITCH_B 2004      // f16 row pitch: 501 words, odd -> 2-way bank = free

// LDS layout (bytes) — NO overlay anymore, everything resident:
//   xg   @ 0      : 64*2004 = 128256
//   errL @ 128256 : err f16 [row][c], pitch 200 B        = 12800
//   hmp  @ 141056 : hm f16x2 [jp][row] u32               = 6400
//   part @ 147456 : f32 [16][64]                         = 4096  -> 151552
#define O_ERR  128256
#define O_HMT  141056
#define O_PART 147456
#define LDS_TOTAL 151552

// Workspace (u32 indices):
//  cluster records: c*80, 80 u32 each:
//   [0..9]  fi[c][0..9]
//   [10..34] wenc_pk[k*5+p] = pk2(W_enc[c][2p][k], W_enc[c][2p+1][k])
//   [35..39] b_enc[c][k] (f32 bits)
//   [40..69] wdec_pk[m*3+q] = pk2(W_dec[c][2q][m], q==2?0:W_dec[c][2q+1][m])
//   [70..79] b_dec[c][m] (f32 bits)
//  meta-enc records @8000: pair p (j0=2p), 52 u32:
//   [0..24]  pk2(We1[2cp][j0],   We1[2cp+1][j0])   cp=0..24
//   [25..49] pk2(We1[2cp][j0+1], We1[2cp+1][j0+1])
//   [50] be1[j0]  [51] be1[j0+1]
//  meta-dec records @9300: cluster c, 26 u32:
//   [0..24]  pk2(Wd1[2jp][c], Wd1[2jp+1][c])  jp=0..24
//   [25] bd1[c]
#define WS_META  8000
#define WS_DEC   9300
#define WS_U32   11900

__device__ __forceinline__ float fdot2(uint32_t a, uint32_t b, float c) {
    return __builtin_amdgcn_fdot2(__builtin_bit_cast(h2, a),
                                  __builtin_bit_cast(h2, b), c, false);
}
__device__ __forceinline__ uint32_t pk2(float a, float b) {
    return __builtin_bit_cast(uint32_t, __builtin_amdgcn_cvt_pkrtz(a, b));
}
__device__ __forceinline__ float h2f(unsigned short u) {
    return (float)__builtin_bit_cast(_Float16, u);
}
__device__ __forceinline__ float asf(uint32_t u) {
    return __builtin_bit_cast(float, u);
}

// ---------------- prep: repack weights into scalar-load-friendly records ----
__global__ void __launch_bounds__(256) prep_kernel(
    const int*   __restrict__ fi,
    const float* __restrict__ W_enc, const float* __restrict__ b_enc,
    const float* __restrict__ W_dec, const float* __restrict__ b_dec,
    const float* __restrict__ We1,   const float* __restrict__ be1,
    const float* __restrict__ Wd1,   const float* __restrict__ bd1,
    uint32_t* __restrict__ ws)
{
    int idx = blockIdx.x * 256 + threadIdx.x;
    if (idx < 8000) {
        int c = idx / 80, r = idx - c * 80;
        uint32_t v;
        if (r < 10) v = (uint32_t)fi[c * 10 + r];
        else if (r < 35) {
            int q = r - 10; int k = q / 5, p = q - k * 5;
            v = pk2(W_enc[c * 50 + (2 * p) * 5 + k],
                    W_enc[c * 50 + (2 * p + 1) * 5 + k]);
        } else if (r < 40) v = __builtin_bit_cast(uint32_t, b_enc[c * 5 + (r - 35)]);
        else if (r < 70) {
            int q = r - 40; int m = q / 3, qq = q - m * 3;
            float lo = W_dec[c * 50 + (2 * qq) * 10 + m];
            float hi = (qq == 2) ? 0.f : W_dec[c * 50 + (2 * qq + 1) * 10 + m];
            v = pk2(lo, hi);
        } else v = __builtin_bit_cast(uint32_t, b_dec[c * 10 + (r - 70)]);
        ws[idx] = v;
    } else if (idx < WS_META + 25 * 52) {
        int t = idx - WS_META; int p = t / 52, r = t - p * 52;
        int j0 = 2 * p;
        uint32_t v;
        if (r < 25)      v = pk2(We1[(2 * r) * 50 + j0], We1[(2 * r + 1) * 50 + j0]);
        else if (r < 50) { int cp = r - 25;
                           v = pk2(We1[(2 * cp) * 50 + j0 + 1], We1[(2 * cp + 1) * 50 + j0 + 1]); }
        else if (r == 50) v = __builtin_bit_cast(uint32_t, be1[j0]);
        else              v = __builtin_bit_cast(uint32_t, be1[j0 + 1]);
        ws[idx] = v;
    } else if (idx < WS_U32) {
        int t = idx - WS_DEC; int c = t / 26, r = t - c * 26;
        uint32_t v;
        if (r < 25) v = pk2(Wd1[(2 * r) * 100 + c], Wd1[(2 * r + 1) * 100 + c]);
        else        v = __builtin_bit_cast(uint32_t, bd1[c]);
        ws[idx] = v;
    }
}

// ---------------- main ------------------------------------------------------
__global__ void __launch_bounds__(1024, 4) kitnet_kernel(
    const float* __restrict__ x,
    const uint32_t* __restrict__ ws,
    float* __restrict__ out)
{
    extern __shared__ char smem[];
    const int tid  = threadIdx.x;
    const int lane = tid & 63;
    const int w    = __builtin_amdgcn_readfirstlane(tid >> 6);

    unsigned short* errL = (unsigned short*)(smem + O_ERR); // pitch 100 u16
    uint32_t* hmp  = (uint32_t*)(smem + O_HMT);             // [p][lane]
    float*    part = (float*)(smem + O_PART);

    // ---- tile staging helpers: loads deep in regs, convert+write later ----
    auto load_x = [&](float4 (&vb)[16], int row0) {
        const float4* xr = (const float4*)(x + (size_t)row0 * 1000);
        #pragma unroll
        for (int k = 0; k < 16; ++k) {
            int i = tid + (k << 10);
            if (i < 16000) vb[k] = xr[i];
        }
    };
    auto write_x = [&](float4 (&vb)[16]) {
        #pragma unroll
        for (int k = 0; k < 16; ++k) {
            int i = tid + (k << 10);
            if (i < 16000) {
                int row = i / 250;
                int c4  = i - row * 250;
                uint32_t* p = (uint32_t*)(smem + row * XPITCH_B + c4 * 8);
                p[0] = pk2(vb[k].x, vb[k].y);
                p[1] = pk2(vb[k].z, vb[k].w);
            }
        }
    };

    const int rowbase = blockIdx.x * (GROUP * TILES);

    // ---- prologue: stage tile 0 (no weight staging needed at all) ----
    float4 vbuf[16];
    load_x(vbuf, rowbase);
    write_x(vbuf);
    __syncthreads();

    // ---- per-cluster AE: x from LDS (11 LDS ops), weights via s_load ----
    const unsigned short* myrow = (const unsigned short*)(smem + lane * XPITCH_B);
    auto do_cluster = [&](int c) {
        const uint32_t* rec = ws + c * 80;      // wave-uniform -> s_load
        uint32_t xpk[5];
        #pragma unroll
        for (int p = 0; p < 5; ++p) {
            int c0 = (int)rec[2 * p], c1 = (int)rec[2 * p + 1];
            xpk[p] = (uint32_t)myrow[c0] | ((uint32_t)myrow[c1] << 16);
        }
        float h[HS];
        #pragma unroll
        for (int k = 0; k < HS; ++k) h[k] = asf(rec[35 + k]);
        #pragma unroll
        for (int k = 0; k < HS; ++k) {
            #pragma unroll
            for (int p = 0; p < 5; ++p)
                h[k] = fdot2(xpk[p], rec[10 + k * 5 + p], h[k]);
        }
        uint32_t hp0 = pk2(fmaxf(h[0], 0.f), fmaxf(h[1], 0.f));
        uint32_t hp1 = pk2(fmaxf(h[2], 0.f), fmaxf(h[3], 0.f));
        uint32_t hp2 = pk2(fmaxf(h[4], 0.f), 0.f);
        float acc = 0.f;
        #pragma unroll
        for (int m = 0; m < M; ++m) {
            float r = asf(rec[70 + m]);
            r = fdot2(hp0, rec[40 + m * 3 + 0], r);
            r = fdot2(hp1, rec[40 + m * 3 + 1], r);
            r = fdot2(hp2, rec[40 + m * 3 + 2], r);
            h2 xv = __builtin_bit_cast(h2, xpk[m >> 1]);
            float xf = (float)((m & 1) ? xv.y : xv.x);
            float d = xf - r;
            acc = __builtin_fmaf(d, d, acc);
        }
        _Float16 ev = (_Float16)__builtin_sqrtf(acc * 0.1f);
        errL[lane * 100 + c] = __builtin_bit_cast(unsigned short, ev);
    };

    const uint2* e2 = (const uint2*)(errL + lane * 100);
    auto do_pair = [&](int p) {
        const uint32_t* mr = ws + WS_META + p * 52;   // wave-uniform -> s_load
        float a0 = asf(mr[50]), a1 = asf(mr[51]);
        #pragma unroll
        for (int ch = 0; ch < 12; ++ch) {
            uint2 e = e2[ch];
            a0 = fdot2(e.x, mr[2 * ch], a0);      a0 = fdot2(e.y, mr[2 * ch + 1], a0);
            a1 = fdot2(e.x, mr[25 + 2 * ch], a1); a1 = fdot2(e.y, mr[25 + 2 * ch + 1], a1);
        }
        uint32_t et = ((const uint32_t*)e2)[24];
        a0 = fdot2(et, mr[24], a0);
        a1 = fdot2(et, mr[49], a1);
        hmp[p * 64 + lane] = pk2(fmaxf(a0, 0.f), fmaxf(a1, 0.f));
    };

    // ================= tile loop: 3 barriers per tile =======================
    #pragma unroll 1
    for (int t = 0; t < TILES; ++t) {
        const int b0t = rowbase + t * GROUP;

        // issue next tile's global loads at tile start (in flight over phase 1)
        if (t + 1 < TILES) load_x(vbuf, b0t + GROUP);

        // ---- phase 1: cluster AEs on tile t ----
        #pragma unroll 1
        for (int u = 0; u < 6; ++u) do_cluster(w + 16 * u);
        if (w < 4) do_cluster(w + 96);
        __syncthreads();                       // A: errL done, xg(t) dead

        // ---- write next tile into xg (xg fully dead; no overlay) ----
        if (t + 1 < TILES) write_x(vbuf);

        // ---- phase 3: meta encoder; j-pair p = w (+16 if w<9) ----
        do_pair(w);
        if (w < 9) do_pair(w + 16);
        __syncthreads();                       // B: hmp done

        // ---- phase 4: meta decoder + final RMS ----
        uint32_t hmreg[25];
        #pragma unroll
        for (int p = 0; p < 25; ++p) hmreg[p] = hmp[p * 64 + lane];
        float facc = 0.f;
        auto do_dec = [&](int c) {
            const uint32_t* dr = ws + WS_DEC + c * 26;  // wave-uniform -> s_load
            float er = h2f(errL[lane * 100 + c]);
            float r = asf(dr[25]);
            #pragma unroll
            for (int q = 0; q < 12; ++q) {
                r = fdot2(hmreg[2 * q], dr[2 * q], r);
                r = fdot2(hmreg[2 * q + 1], dr[2 * q + 1], r);
            }
            r = fdot2(hmreg[24], dr[24], r);
            float d = er - r;
            facc = __builtin_fmaf(d, d, facc);
        };
        #pragma unroll 2
        for (int u = 0; u < 6; ++u) do_dec(w + 16 * u);
        if (w < 4) do_dec(w + 96);
        part[w * 64 + lane] = facc;
        __syncthreads();                       // C: part done, errL reads done

        // ---- reduce + store; other waves roll into next tile's phase 1 ----
        if (tid < 64) {
            float s = 0.f;
            #pragma unroll
            for (int i = 0; i < NWAVE; ++i) s += part[i * 64 + tid];
            float fe = __builtin_sqrtf(s * 0.01f);
            out[b0t + tid] = 1.f / (1.f + __expf(-fe));
        }
    }
}

extern "C" void kernel_launch(void* const* d_in, const int* in_sizes, int n_in,
                              void* d_out, int out_size, void* d_ws, size_t ws_size,
                              hipStream_t stream) {
    const float* x     = (const float*)d_in[0];
    const int*   fi    = (const int*)  d_in[1];
    const float* W_enc = (const float*)d_in[2];
    const float* b_enc = (const float*)d_in[3];
    const float* W_dec = (const float*)d_in[4];
    const float* b_dec = (const float*)d_in[5];
    const float* We1   = (const float*)d_in[6];
    const float* be1   = (const float*)d_in[7];
    const float* Wd1   = (const float*)d_in[8];
    const float* bd1   = (const float*)d_in[9];
    float* out = (float*)d_out;
    uint32_t* ws = (uint32_t*)d_ws;
    (void)ws_size;

    prep_kernel<<<(WS_U32 + 255) / 256, 256, 0, stream>>>(
        fi, W_enc, b_enc, W_dec, b_dec, We1, be1, Wd1, bd1, ws);

    (void)hipFuncSetAttribute((const void*)kitnet_kernel,
                              hipFuncAttributeMaxDynamicSharedMemorySize, LDS_TOTAL);
    kitnet_kernel<<<65536 / (GROUP * TILES), 1024, LDS_TOTAL, stream>>>(x, ws, out);
}